// Round 2
// baseline (106.057 us; speedup 1.0000x reference)
//
#include <hip/hip_runtime.h>

#define NB    4
#define DIN_  64
#define DOUT_ 64
#define KN    16
#define NPT   8192
#define CPAD  264   // 256 c-entries + 8 pad shorts; rows 528B (16B-aligned)

typedef __attribute__((ext_vector_type(8))) short short8;
typedef __attribute__((ext_vector_type(4))) float v4f;

__device__ __forceinline__ float bf2f(unsigned short u) {
    unsigned int x = ((unsigned int)u) << 16;
    float f; __builtin_memcpy(&f, &x, 4); return f;
}
__device__ __forceinline__ unsigned short f2bf(float f) {
    unsigned int x; __builtin_memcpy(&x, &f, 4);
    x += 0x7fffu + ((x >> 16) & 1u);   // RNE
    return (unsigned short)(x >> 16);
}

// ---------- prep: 3 jobs in one dispatch ----------
// blocks [0,512):  feat fp32 [B][64][N] -> ft bf16 [B][N][64]
// blocks [512,640): pos fp32 [B][3][N]  -> pt float4 (x,y,z,1)
// blocks [640,648): theta/pbias -> tbf bf16 [64][256]  (Tt[o][c], c=p*64+i; c>=192 -> pbias)
__global__ void k_prep(const float* __restrict__ feat, const float* __restrict__ pos,
                       const float* __restrict__ theta, const float* __restrict__ pbias,
                       unsigned short* __restrict__ ft, float4* __restrict__ pt,
                       unsigned short* __restrict__ tbf) {
    __shared__ float tile[64][65];
    const int bid = blockIdx.x;
    if (bid < 512) {
        int b = bid >> 7, n0 = (bid & 127) << 6;
        int lane = threadIdx.x & 63, w = threadIdx.x >> 6;
#pragma unroll
        for (int r = 0; r < 16; ++r) {
            int i = (r << 2) | w;
            tile[i][lane] = feat[(b*DIN_ + i)*NPT + n0 + lane];
        }
        __syncthreads();
#pragma unroll
        for (int r = 0; r < 16; ++r) {
            int n = (r << 2) | w;
            ft[((size_t)(b*NPT + n0 + n))*DIN_ + lane] = f2bf(tile[lane][n]);
        }
    } else if (bid < 640) {
        int t = (bid - 512)*256 + threadIdx.x;   // 0..32767
        int b = t >> 13, n = t & 8191;
        float4 v;
        v.x = pos[(b*3 + 0)*NPT + n];
        v.y = pos[(b*3 + 1)*NPT + n];
        v.z = pos[(b*3 + 2)*NPT + n];
        v.w = 1.0f;
        pt[t] = v;
    } else {
        int e = (bid - 640)*256 + threadIdx.x;   // 0..2047
        int o = e >> 5, g = e & 31;
        short8 u;
#pragma unroll
        for (int j = 0; j < 8; ++j) {
            int c = g*8 + j;
            float v = (c < 192) ? theta[c*64 + o] : pbias[(c - 192)*64 + o];
            u[j] = (short)f2bf(v);
        }
        *reinterpret_cast<short8*>(tbf + o*256 + g*8) = u;   // 16B aligned
    }
}

// ---------- main: gather+contract (no cross-lane) -> Xt LDS -> MFMA epilogue ----------
// Stage 1 layout (this round): lane = (p8 = lane>>3, j8 = lane&7).
// Each lane owns (point q = w*8 + p8, feature chunk [j8*8, j8*8+8)).
// One pass, 8 points/wave, 16B ushort8 ft gathers -> 32 VMEM/wave (was 64).
template<bool USE_WS>
__global__ __launch_bounds__(256, 4) void k_main(
    const float*          __restrict__ feat,
    const float*          __restrict__ pos,
    const int*            __restrict__ nbr,
    const float*          __restrict__ theta,
    const float*          __restrict__ pbias,
    const float*          __restrict__ fbias,
    const unsigned short* __restrict__ ft,
    const float4*         __restrict__ pt,
    const unsigned short* __restrict__ tbf,
    float*                __restrict__ out)
{
    __shared__ __align__(16) unsigned short Xt[32*CPAD];  // 16896 B  [q][c]
    __shared__ int    nbs[KN*32];                         // 2048 B   [k][q]
    __shared__ float4 pcs[32];                            // 512 B

    const int tid  = threadIdx.x;
    const int lane = tid & 63;
    const int w    = tid >> 6;
    const int j16  = lane & 15;
    const int pt2  = lane >> 4;    // epilogue: quad (kg)
    const int j8   = lane & 7;     // stage1: feature chunk
    const int p8   = lane >> 3;    // stage1: point within wave

    const int base = blockIdx.x << 5;   // 32 points/block; 8192%32==0 -> single batch
    const int b    = base >> 13;
    const int nb0  = base & 8191;

    // ---- cooperative preamble: nbr slab + center positions ----
#pragma unroll
    for (int r = 0; r < 2; ++r) {
        int idx = tid + (r << 8);            // 0..511
        int k = idx >> 5, c = idx & 31;
        nbs[idx] = nbr[(b*KN + k)*NPT + nb0 + c];
    }
    if (tid < 128) {
        if (USE_WS) {
            ((float*)pcs)[tid] = ((const float*)(pt + b*NPT + nb0))[tid];
        } else if (tid < 32) {
            int n = nb0 + tid;
            pcs[tid] = make_float4(pos[(b*3+0)*NPT + n], pos[(b*3+1)*NPT + n],
                                   pos[(b*3+2)*NPT + n], 1.0f);
        }
    }
    __syncthreads();

    const unsigned short* ftb = ft + (((size_t)b) << 19);   // b*NPT*64
    const float4*         ptb = pt + b*NPT;

    // ---- stage 1: single pass, 8 points per wave, 8 features per lane ----
    {
        const int q = (w << 3) + p8;
        const float4 pc = pcs[q];

        // Prefetch all neighbor ids into VGPRs (broadcast ds_read, 8 lanes share).
        // k-loop fully unrolled so ids[] stays compile-time-indexed.
        int ids[KN];
#pragma unroll
        for (int k = 0; k < KN; ++k) ids[k] = nbs[(k << 5) + q];

        float acc[4][8];
#pragma unroll
        for (int p = 0; p < 4; ++p)
#pragma unroll
            for (int j = 0; j < 8; ++j) acc[p][j] = 0.f;

#pragma unroll
        for (int k = 0; k < KN; ++k) {
            const int id = ids[k];
            float4 pg; float f[8];
            if (USE_WS) {
                pg = ptb[id];
                short8 fr = *reinterpret_cast<const short8*>(
                    ftb + (((size_t)id) << 6) + (j8 << 3));   // 16B, aligned
#pragma unroll
                for (int j = 0; j < 8; ++j) f[j] = bf2f((unsigned short)fr[j]);
            } else {
                pg.x = pos[(b*3+0)*NPT + id];
                pg.y = pos[(b*3+1)*NPT + id];
                pg.z = pos[(b*3+2)*NPT + id];
                pg.w = 1.0f;
#pragma unroll
                for (int j = 0; j < 8; ++j)
                    f[j] = feat[(b*DIN_ + (j8<<3) + j)*NPT + id];
            }
#pragma unroll
            for (int j = 0; j < 8; ++j) {
                acc[0][j] += pg.x * f[j];
                acc[1][j] += pg.y * f[j];
                acc[2][j] += pg.z * f[j];
                acc[3][j] += f[j];
            }
        }
        // center correction: M_p -= pc_p * S
#pragma unroll
        for (int j = 0; j < 8; ++j) {
            acc[0][j] -= pc.x * acc[3][j];
            acc[1][j] -= pc.y * acc[3][j];
            acc[2][j] -= pc.z * acc[3][j];
        }
        // write X[q][c], c = p*64 + j8*8 + j  (bf16, 16B stores)
#pragma unroll
        for (int p = 0; p < 4; ++p) {
            short8 pk;
#pragma unroll
            for (int j = 0; j < 8; ++j) pk[j] = (short)f2bf(acc[p][j]);
            *reinterpret_cast<short8*>(&Xt[q*CPAD + (p<<6) + (j8<<3)]) = pk;
        }
    }
    __syncthreads();

    // ---- epilogue: wave w -> o-rows [16w,16w+16); A-frags straight from L2-hot tbf ----
    const int kg   = pt2;                 // mfma quad
    const int orow = (w << 4) + j16;      // A: m = lane&15
    v4f acc0 = {0.f,0.f,0.f,0.f}, acc1 = {0.f,0.f,0.f,0.f};
#pragma unroll
    for (int ks = 0; ks < 8; ++ks) {
        const int koff = (ks << 5) + (kg << 3);   // k = quad*8 + j
        short8 a;
        if (USE_WS) {
            a = *reinterpret_cast<const short8*>(tbf + orow*256 + koff);
        } else {
#pragma unroll
            for (int j = 0; j < 8; ++j) {
                int c = koff + j;
                float v = (c < 192) ? theta[c*64 + orow] : pbias[(c - 192)*64 + orow];
                a[j] = (short)f2bf(v);
            }
        }
        short8 b0 = *reinterpret_cast<const short8*>(&Xt[j16*CPAD + koff]);
        short8 b1 = *reinterpret_cast<const short8*>(&Xt[(16 + j16)*CPAD + koff]);
        acc0 = __builtin_amdgcn_mfma_f32_16x16x32_bf16(a, b0, acc0, 0, 0, 0);
        acc1 = __builtin_amdgcn_mfma_f32_16x16x32_bf16(a, b1, acc1, 0, 0, 0);
    }
    // C/D: col=lane&15 (point), row=quad*4+reg (o)
#pragma unroll
    for (int r = 0; r < 4; ++r) {
        const int o = (w << 4) + (kg << 2) + r;
        const float fb = fbias[o];
        const size_t rowoff = (size_t)(b*DOUT_ + o)*NPT + nb0;
        out[rowoff + j16]      = acc0[r] + fb;
        out[rowoff + 16 + j16] = acc1[r] + fb;
    }
}

extern "C" void kernel_launch(void* const* d_in, const int* in_sizes, int n_in,
                              void* d_out, int out_size, void* d_ws, size_t ws_size,
                              hipStream_t stream) {
    const float* feat  = (const float*)d_in[0];
    const float* pos   = (const float*)d_in[1];
    const int*   nbr   = (const int*)d_in[2];
    const float* theta = (const float*)d_in[3];
    const float* pbias = (const float*)d_in[4];
    const float* fbias = (const float*)d_in[5];
    float* out = (float*)d_out;

    const size_t ft_bytes  = (size_t)NB*NPT*DIN_*2;          // 4 MiB
    const size_t pt_bytes  = (size_t)NB*NPT*sizeof(float4);  // 512 KiB
    const size_t tbf_bytes = (size_t)DOUT_*256*2;            // 32 KiB
    const int n_blocks = (NB*NPT)/32;                        // 1024

    if (ws_size >= ft_bytes + pt_bytes + tbf_bytes) {
        unsigned short* ft  = (unsigned short*)d_ws;
        float4*         pt  = (float4*)((char*)d_ws + ft_bytes);
        unsigned short* tbf = (unsigned short*)((char*)d_ws + ft_bytes + pt_bytes);
        k_prep<<<648, 256, 0, stream>>>(feat, pos, theta, pbias, ft, pt, tbf);
        k_main<true><<<n_blocks, 256, 0, stream>>>(feat, pos, nbr, theta, pbias, fbias,
                                                   ft, pt, tbf, out);
    } else {
        k_main<false><<<n_blocks, 256, 0, stream>>>(feat, pos, nbr, theta, pbias, fbias,
                                                    (const unsigned short*)feat,
                                                    (const float4*)feat,
                                                    (const unsigned short*)feat, out);
    }
}

// Round 3
// 92.541 us; speedup vs baseline: 1.1461x; 1.1461x over previous
//
#include <hip/hip_runtime.h>

#define NB    4
#define DIN_  64
#define DOUT_ 64
#define KN    16
#define NPT   8192
#define PTS   16    // points per block (was 32): 1 stage-1 pass per wave, 2x blocks
#define CPAD  264   // 256 c-entries + 8 pad shorts; rows 528B (16B-aligned)

typedef __attribute__((ext_vector_type(8))) short short8;
typedef __attribute__((ext_vector_type(4))) float v4f;

__device__ __forceinline__ float bf2f(unsigned short u) {
    unsigned int x = ((unsigned int)u) << 16;
    float f; __builtin_memcpy(&f, &x, 4); return f;
}
__device__ __forceinline__ unsigned short f2bf(float f) {
    unsigned int x; __builtin_memcpy(&x, &f, 4);
    x += 0x7fffu + ((x >> 16) & 1u);   // RNE
    return (unsigned short)(x >> 16);
}

// ---------- prep: 3 jobs in one dispatch ----------
// blocks [0,512):  feat fp32 [B][64][N] -> ft bf16 [B][N][64]
// blocks [512,640): pos fp32 [B][3][N]  -> pt float4 (x,y,z,1)
// blocks [640,648): theta/pbias -> tbf bf16 [64][256]  (Tt[o][c], c=p*64+i; c>=192 -> pbias)
__global__ void k_prep(const float* __restrict__ feat, const float* __restrict__ pos,
                       const float* __restrict__ theta, const float* __restrict__ pbias,
                       unsigned short* __restrict__ ft, float4* __restrict__ pt,
                       unsigned short* __restrict__ tbf) {
    __shared__ float tile[64][65];
    const int bid = blockIdx.x;
    if (bid < 512) {
        int b = bid >> 7, n0 = (bid & 127) << 6;
        int lane = threadIdx.x & 63, w = threadIdx.x >> 6;
#pragma unroll
        for (int r = 0; r < 16; ++r) {
            int i = (r << 2) | w;
            tile[i][lane] = feat[(b*DIN_ + i)*NPT + n0 + lane];
        }
        __syncthreads();
#pragma unroll
        for (int r = 0; r < 16; ++r) {
            int n = (r << 2) | w;
            ft[((size_t)(b*NPT + n0 + n))*DIN_ + lane] = f2bf(tile[lane][n]);
        }
    } else if (bid < 640) {
        int t = (bid - 512)*256 + threadIdx.x;   // 0..32767
        int b = t >> 13, n = t & 8191;
        float4 v;
        v.x = pos[(b*3 + 0)*NPT + n];
        v.y = pos[(b*3 + 1)*NPT + n];
        v.z = pos[(b*3 + 2)*NPT + n];
        v.w = 1.0f;
        pt[t] = v;
    } else {
        int e = (bid - 640)*256 + threadIdx.x;   // 0..2047
        int o = e >> 5, g = e & 31;
        short8 u;
#pragma unroll
        for (int j = 0; j < 8; ++j) {
            int c = g*8 + j;
            float v = (c < 192) ? theta[c*64 + o] : pbias[(c - 192)*64 + o];
            u[j] = (short)f2bf(v);
        }
        *reinterpret_cast<short8*>(tbf + o*256 + g*8) = u;   // 16B aligned
    }
}

// ---------- main: gather+contract -> Xt LDS -> MFMA epilogue ----------
// This round: 16 points/block, 2048 blocks. Each wave: ONE stage-1 pass
// (4 points, 16 lanes each, 4-feature chunks). __launch_bounds__(256,8)
// targets <=64 VGPR -> 8 waves/SIMD (32/CU, 2x prev) to hide gather latency
// by TLP instead of ILP (R2 showed ILP-via-registers backfires).
template<bool USE_WS>
__global__ __launch_bounds__(256, 8) void k_main(
    const float*          __restrict__ feat,
    const float*          __restrict__ pos,
    const int*            __restrict__ nbr,
    const float*          __restrict__ theta,
    const float*          __restrict__ pbias,
    const float*          __restrict__ fbias,
    const unsigned short* __restrict__ ft,
    const float4*         __restrict__ pt,
    const unsigned short* __restrict__ tbf,
    float*                __restrict__ out)
{
    __shared__ __align__(16) unsigned short Xt[PTS*CPAD];  // 8448 B  [q][c]
    __shared__ int    nbs[KN*PTS];                         // 1024 B  [k][q]
    __shared__ float4 pcs[PTS];                            // 256 B

    const int tid  = threadIdx.x;
    const int lane = tid & 63;
    const int w    = tid >> 6;
    const int j16  = lane & 15;
    const int pt2  = lane >> 4;    // stage1: point in wave; epilogue: quad (kg)

    const int base = blockIdx.x << 4;   // 16 points/block; 8192%16==0 -> single batch
    const int b    = base >> 13;
    const int nb0  = base & 8191;

    // ---- cooperative preamble: nbr slab + center positions ----
    if (tid < KN*PTS) {
        int k = tid >> 4, c = tid & 15;
        nbs[tid] = nbr[(b*KN + k)*NPT + nb0 + c];
    }
    if (tid >= 192) {   // separate wave from the nbr loads; 64 lanes
        int t = tid - 192;
        if (USE_WS) {
            ((float*)pcs)[t] = ((const float*)(pt + b*NPT + nb0))[t];
        } else if (t < PTS) {
            int n = nb0 + t;
            pcs[t] = make_float4(pos[(b*3+0)*NPT + n], pos[(b*3+1)*NPT + n],
                                 pos[(b*3+2)*NPT + n], 1.0f);
        }
    }
    __syncthreads();

    const unsigned short* ftb = ft + (((size_t)b) << 19);   // b*NPT*64
    const float4*         ptb = pt + b*NPT;

    // ---- stage 1: single pass; wave w owns points q = w*4 + pt2 ----
    {
        const int q = (w << 2) + pt2;
        const float4 pc = pcs[q];
        float acc[4][4];
#pragma unroll
        for (int p = 0; p < 4; ++p)
#pragma unroll
            for (int j = 0; j < 4; ++j) acc[p][j] = 0.f;

#pragma unroll 2
        for (int k = 0; k < KN; ++k) {
            const int id = nbs[(k << 4) + q];      // LDS broadcast (16 lanes share)
            float4 pg; float f[4];
            if (USE_WS) {
                pg = ptb[id];
                ushort4 fr = *reinterpret_cast<const ushort4*>(
                    ftb + (((size_t)id) << 6) + (j16 << 2));
                f[0]=bf2f(fr.x); f[1]=bf2f(fr.y); f[2]=bf2f(fr.z); f[3]=bf2f(fr.w);
            } else {
                pg.x = pos[(b*3+0)*NPT + id];
                pg.y = pos[(b*3+1)*NPT + id];
                pg.z = pos[(b*3+2)*NPT + id];
                pg.w = 1.0f;
#pragma unroll
                for (int j = 0; j < 4; ++j)
                    f[j] = feat[(b*DIN_ + (j16<<2) + j)*NPT + id];
            }
#pragma unroll
            for (int j = 0; j < 4; ++j) {
                acc[0][j] += pg.x * f[j];
                acc[1][j] += pg.y * f[j];
                acc[2][j] += pg.z * f[j];
                acc[3][j] += f[j];
            }
        }
        // center correction: M_p -= pc_p * S
#pragma unroll
        for (int j = 0; j < 4; ++j) {
            acc[0][j] -= pc.x * acc[3][j];
            acc[1][j] -= pc.y * acc[3][j];
            acc[2][j] -= pc.z * acc[3][j];
        }
        // write X[q][c], c = p*64 + j16*4 + j  (bf16)
#pragma unroll
        for (int p = 0; p < 4; ++p) {
            ushort4 pk;
            pk.x = f2bf(acc[p][0]); pk.y = f2bf(acc[p][1]);
            pk.z = f2bf(acc[p][2]); pk.w = f2bf(acc[p][3]);
            *reinterpret_cast<ushort4*>(&Xt[q*CPAD + (p<<6) + (j16<<2)]) = pk;
        }
    }
    __syncthreads();

    // ---- epilogue: wave w -> o-rows [16w,16w+16); A-frags from L2-hot tbf ----
    const int kg   = pt2;                 // mfma quad
    const int orow = (w << 4) + j16;      // A: m = lane&15
    v4f acc0 = {0.f,0.f,0.f,0.f};
#pragma unroll
    for (int ks = 0; ks < 8; ++ks) {
        const int koff = (ks << 5) + (kg << 3);   // k = quad*8 + j
        short8 a;
        if (USE_WS) {
            a = *reinterpret_cast<const short8*>(tbf + orow*256 + koff);
        } else {
#pragma unroll
            for (int j = 0; j < 8; ++j) {
                int c = koff + j;
                float v = (c < 192) ? theta[c*64 + orow] : pbias[(c - 192)*64 + orow];
                a[j] = (short)f2bf(v);
            }
        }
        short8 b0 = *reinterpret_cast<const short8*>(&Xt[j16*CPAD + koff]);
        acc0 = __builtin_amdgcn_mfma_f32_16x16x32_bf16(a, b0, acc0, 0, 0, 0);
    }
    // C/D: col=lane&15 (point), row=quad*4+reg (o)
#pragma unroll
    for (int r = 0; r < 4; ++r) {
        const int o = (w << 4) + (kg << 2) + r;
        const float fb = fbias[o];
        out[(size_t)(b*DOUT_ + o)*NPT + nb0 + j16] = acc0[r] + fb;
    }
}

extern "C" void kernel_launch(void* const* d_in, const int* in_sizes, int n_in,
                              void* d_out, int out_size, void* d_ws, size_t ws_size,
                              hipStream_t stream) {
    const float* feat  = (const float*)d_in[0];
    const float* pos   = (const float*)d_in[1];
    const int*   nbr   = (const int*)d_in[2];
    const float* theta = (const float*)d_in[3];
    const float* pbias = (const float*)d_in[4];
    const float* fbias = (const float*)d_in[5];
    float* out = (float*)d_out;

    const size_t ft_bytes  = (size_t)NB*NPT*DIN_*2;          // 4 MiB
    const size_t pt_bytes  = (size_t)NB*NPT*sizeof(float4);  // 512 KiB
    const size_t tbf_bytes = (size_t)DOUT_*256*2;            // 32 KiB
    const int n_blocks = (NB*NPT)/PTS;                       // 2048

    if (ws_size >= ft_bytes + pt_bytes + tbf_bytes) {
        unsigned short* ft  = (unsigned short*)d_ws;
        float4*         pt  = (float4*)((char*)d_ws + ft_bytes);
        unsigned short* tbf = (unsigned short*)((char*)d_ws + ft_bytes + pt_bytes);
        k_prep<<<648, 256, 0, stream>>>(feat, pos, theta, pbias, ft, pt, tbf);
        k_main<true><<<n_blocks, 256, 0, stream>>>(feat, pos, nbr, theta, pbias, fbias,
                                                   ft, pt, tbf, out);
    } else {
        k_main<false><<<n_blocks, 256, 0, stream>>>(feat, pos, nbr, theta, pbias, fbias,
                                                    (const unsigned short*)feat,
                                                    (const float4*)feat,
                                                    (const unsigned short*)feat, out);
    }
}

// Round 4
// 89.621 us; speedup vs baseline: 1.1834x; 1.0326x over previous
//
#include <hip/hip_runtime.h>
#include <hip/hip_cooperative_groups.h>

namespace cg = cooperative_groups;

#define NB    4
#define DIN_  64
#define DOUT_ 64
#define KN    16
#define NPT   8192
#define CPAD  264   // 256 c-entries + 8 pad shorts; rows 528B (16B-aligned)

typedef __attribute__((ext_vector_type(8))) short short8;
typedef __attribute__((ext_vector_type(4))) float v4f;

__device__ __forceinline__ float bf2f(unsigned short u) {
    unsigned int x = ((unsigned int)u) << 16;
    float f; __builtin_memcpy(&f, &x, 4); return f;
}
__device__ __forceinline__ unsigned short f2bf(float f) {
    unsigned int x; __builtin_memcpy(&x, &f, 4);
    x += 0x7fffu + ((x >> 16) & 1u);   // RNE
    return (unsigned short)(x >> 16);
}

// ---------- standalone prep (fallback path only) ----------
__global__ void k_prep(const float* __restrict__ feat, const float* __restrict__ pos,
                       const float* __restrict__ theta, const float* __restrict__ pbias,
                       unsigned short* __restrict__ ft, float4* __restrict__ pt,
                       unsigned short* __restrict__ tbf) {
    __shared__ float tile[64][65];
    const int bid = blockIdx.x;
    if (bid < 512) {
        int b = bid >> 7, n0 = (bid & 127) << 6;
        int lane = threadIdx.x & 63, w = threadIdx.x >> 6;
#pragma unroll
        for (int r = 0; r < 16; ++r) {
            int i = (r << 2) | w;
            tile[i][lane] = feat[(b*DIN_ + i)*NPT + n0 + lane];
        }
        __syncthreads();
#pragma unroll
        for (int r = 0; r < 16; ++r) {
            int n = (r << 2) | w;
            ft[((size_t)(b*NPT + n0 + n))*DIN_ + lane] = f2bf(tile[lane][n]);
        }
    } else if (bid < 640) {
        int t = (bid - 512)*256 + threadIdx.x;   // 0..32767
        int b = t >> 13, n = t & 8191;
        float4 v;
        v.x = pos[(b*3 + 0)*NPT + n];
        v.y = pos[(b*3 + 1)*NPT + n];
        v.z = pos[(b*3 + 2)*NPT + n];
        v.w = 1.0f;
        pt[t] = v;
    } else {
        int e = (bid - 640)*256 + threadIdx.x;   // 0..2047
        int o = e >> 5, g = e & 31;
        short8 u;
#pragma unroll
        for (int j = 0; j < 8; ++j) {
            int c = g*8 + j;
            float v = (c < 192) ? theta[c*64 + o] : pbias[(c - 192)*64 + o];
            u[j] = (short)f2bf(v);
        }
        *reinterpret_cast<short8*>(tbf + o*256 + g*8) = u;   // 16B aligned
    }
}

// ---------- fused kernel ----------
// MODE 0: main only, USE_WS (fallback after k_prep)
// MODE 1: cooperative: prep phase + grid.sync + main (USE_WS)
// MODE 2: main only, no workspace
template<int MODE>
__global__ __launch_bounds__(256, 4) void k_fused(
    const float*    __restrict__ feat,
    const float*    __restrict__ pos,
    const int*      __restrict__ nbr,
    const float*    __restrict__ theta,
    const float*    __restrict__ pbias,
    const float*    __restrict__ fbias,
    unsigned short* __restrict__ ft,
    float4*         __restrict__ pt,
    unsigned short* __restrict__ tbf,
    float*          __restrict__ out)
{
    constexpr bool USE_WS = (MODE != 2);

    __shared__ __align__(16) unsigned short Xt[32*CPAD];  // 16896 B  [q][c]
    __shared__ int    nbs[KN*32];                         // 2048 B   [k][q]
    __shared__ float4 pcs[32];                            // 512 B

    const int tid  = threadIdx.x;
    const int lane = tid & 63;
    const int w    = tid >> 6;
    const int j16  = lane & 15;
    const int pt2  = lane >> 4;    // stage1: which of 4 points; epilogue: quad (kg)
    const int bid  = blockIdx.x;

    if constexpr (MODE == 1) {
        // ---- phase A: prep, distributed over blocks [0,648); rest idle to sync ----
        if (bid < 512) {
            // reuse Xt as the f32 transpose tile (16640 B <= 16896 B)
            float (*tile)[65] = reinterpret_cast<float(*)[65]>(Xt);
            int b = bid >> 7, n0 = (bid & 127) << 6;
#pragma unroll
            for (int r = 0; r < 16; ++r) {
                int i = (r << 2) | w;
                tile[i][lane] = feat[(b*DIN_ + i)*NPT + n0 + lane];
            }
            __syncthreads();
#pragma unroll
            for (int r = 0; r < 16; ++r) {
                int n = (r << 2) | w;
                ft[((size_t)(b*NPT + n0 + n))*DIN_ + lane] = f2bf(tile[lane][n]);
            }
        } else if (bid < 640) {
            int t = (bid - 512)*256 + tid;       // 0..32767
            int b = t >> 13, n = t & 8191;
            float4 v;
            v.x = pos[(b*3 + 0)*NPT + n];
            v.y = pos[(b*3 + 1)*NPT + n];
            v.z = pos[(b*3 + 2)*NPT + n];
            v.w = 1.0f;
            pt[t] = v;
        } else if (bid < 648) {
            int e = (bid - 640)*256 + tid;       // 0..2047
            int o = e >> 5, g = e & 31;
            short8 u;
#pragma unroll
            for (int j = 0; j < 8; ++j) {
                int c = g*8 + j;
                float v = (c < 192) ? theta[c*64 + o] : pbias[(c - 192)*64 + o];
                u[j] = (short)f2bf(v);
            }
            *reinterpret_cast<short8*>(tbf + o*256 + g*8) = u;
        }
        cg::this_grid().sync();   // all 1024 blocks; release/acquire for ft/pt/tbf
    }

    // ---- phase B: main (identical to the 89.4us R0 k_main body) ----
    const int base = bid << 5;   // 32 points/block; 8192%32==0 -> single batch
    const int b    = base >> 13;
    const int nb0  = base & 8191;

    // cooperative preamble: nbr slab + center positions
#pragma unroll
    for (int r = 0; r < 2; ++r) {
        int idx = tid + (r << 8);            // 0..511
        int k = idx >> 5, c = idx & 31;
        nbs[idx] = nbr[(b*KN + k)*NPT + nb0 + c];
    }
    if (tid < 128) {
        if (USE_WS) {
            ((float*)pcs)[tid] = ((const float*)(pt + b*NPT + nb0))[tid];
        } else if (tid < 32) {
            int n = nb0 + tid;
            pcs[tid] = make_float4(pos[(b*3+0)*NPT + n], pos[(b*3+1)*NPT + n],
                                   pos[(b*3+2)*NPT + n], 1.0f);
        }
    }
    __syncthreads();

    const unsigned short* ftb = ft + (((size_t)b) << 19);   // b*NPT*64

    // stage 1: 2 passes x 4 points per wave; lane owns (point, 4-feature chunk)
#pragma unroll
    for (int pass = 0; pass < 2; ++pass) {
        const int q = (w << 3) + (pass << 2) + pt2;
        const float4 pc = pcs[q];
        float acc[4][4];
#pragma unroll
        for (int p = 0; p < 4; ++p)
#pragma unroll
            for (int j = 0; j < 4; ++j) acc[p][j] = 0.f;

#pragma unroll 4
        for (int k = 0; k < KN; ++k) {
            const int id = nbs[(k << 5) + q];      // LDS broadcast (16 lanes share)
            float4 pg; float f[4];
            if (USE_WS) {
                pg = pt[b*NPT + id];
                ushort4 fr = *reinterpret_cast<const ushort4*>(
                    ftb + (((size_t)id) << 6) + (j16 << 2));
                f[0]=bf2f(fr.x); f[1]=bf2f(fr.y); f[2]=bf2f(fr.z); f[3]=bf2f(fr.w);
            } else {
                pg.x = pos[(b*3+0)*NPT + id];
                pg.y = pos[(b*3+1)*NPT + id];
                pg.z = pos[(b*3+2)*NPT + id];
                pg.w = 1.0f;
#pragma unroll
                for (int j = 0; j < 4; ++j)
                    f[j] = feat[(b*DIN_ + (j16<<2) + j)*NPT + id];
            }
#pragma unroll
            for (int j = 0; j < 4; ++j) {
                acc[0][j] += pg.x * f[j];
                acc[1][j] += pg.y * f[j];
                acc[2][j] += pg.z * f[j];
                acc[3][j] += f[j];
            }
        }
        // center correction: M_p -= pc_p * S
#pragma unroll
        for (int j = 0; j < 4; ++j) {
            acc[0][j] -= pc.x * acc[3][j];
            acc[1][j] -= pc.y * acc[3][j];
            acc[2][j] -= pc.z * acc[3][j];
        }
        // write X[q][c], c = p*64 + j16*4 + j  (bf16)
#pragma unroll
        for (int p = 0; p < 4; ++p) {
            ushort4 pk;
            pk.x = f2bf(acc[p][0]); pk.y = f2bf(acc[p][1]);
            pk.z = f2bf(acc[p][2]); pk.w = f2bf(acc[p][3]);
            *reinterpret_cast<ushort4*>(&Xt[q*CPAD + (p<<6) + (j16<<2)]) = pk;
        }
    }
    __syncthreads();

    // epilogue: wave w -> o-rows [16w,16w+16); A-frags from L2-hot tbf
    const int kg   = pt2;                 // mfma quad
    const int orow = (w << 4) + j16;      // A: m = lane&15
    v4f acc0 = {0.f,0.f,0.f,0.f}, acc1 = {0.f,0.f,0.f,0.f};
#pragma unroll
    for (int ks = 0; ks < 8; ++ks) {
        const int koff = (ks << 5) + (kg << 3);   // k = quad*8 + j
        short8 a;
        if (USE_WS) {
            a = *reinterpret_cast<const short8*>(tbf + orow*256 + koff);
        } else {
#pragma unroll
            for (int j = 0; j < 8; ++j) {
                int c = koff + j;
                float v = (c < 192) ? theta[c*64 + orow] : pbias[(c - 192)*64 + orow];
                a[j] = (short)f2bf(v);
            }
        }
        short8 b0 = *reinterpret_cast<const short8*>(&Xt[j16*CPAD + koff]);
        short8 b1 = *reinterpret_cast<const short8*>(&Xt[(16 + j16)*CPAD + koff]);
        acc0 = __builtin_amdgcn_mfma_f32_16x16x32_bf16(a, b0, acc0, 0, 0, 0);
        acc1 = __builtin_amdgcn_mfma_f32_16x16x32_bf16(a, b1, acc1, 0, 0, 0);
    }
    // C/D: col=lane&15 (point), row=quad*4+reg (o)
#pragma unroll
    for (int r = 0; r < 4; ++r) {
        const int o = (w << 4) + (kg << 2) + r;
        const float fb = fbias[o];
        const size_t rowoff = (size_t)(b*DOUT_ + o)*NPT + nb0;
        out[rowoff + j16]      = acc0[r] + fb;
        out[rowoff + 16 + j16] = acc1[r] + fb;
    }
}

extern "C" void kernel_launch(void* const* d_in, const int* in_sizes, int n_in,
                              void* d_out, int out_size, void* d_ws, size_t ws_size,
                              hipStream_t stream) {
    const float* feat  = (const float*)d_in[0];
    const float* pos   = (const float*)d_in[1];
    const int*   nbr   = (const int*)d_in[2];
    const float* theta = (const float*)d_in[3];
    const float* pbias = (const float*)d_in[4];
    const float* fbias = (const float*)d_in[5];
    float* out = (float*)d_out;

    const size_t ft_bytes  = (size_t)NB*NPT*DIN_*2;          // 4 MiB
    const size_t pt_bytes  = (size_t)NB*NPT*sizeof(float4);  // 512 KiB
    const size_t tbf_bytes = (size_t)DOUT_*256*2;            // 32 KiB
    const int n_blocks = (NB*NPT)/32;                        // 1024

    if (ws_size >= ft_bytes + pt_bytes + tbf_bytes) {
        unsigned short* ft  = (unsigned short*)d_ws;
        float4*         pt  = (float4*)((char*)d_ws + ft_bytes);
        unsigned short* tbf = (unsigned short*)((char*)d_ws + ft_bytes + pt_bytes);

        // one-time co-residency check for the cooperative fused path
        static int coop = -1;
        if (coop < 0) {
            int nb = 0;
            hipError_t e = hipOccupancyMaxActiveBlocksPerMultiprocessor(
                &nb, reinterpret_cast<const void*>(&k_fused<1>), 256, 0);
            coop = (e == hipSuccess && nb >= 4) ? 1 : 0;   // 4 blocks/CU x 256 CU >= 1024
        }

        if (coop) {
            void* args[] = { (void*)&feat, (void*)&pos, (void*)&nbr, (void*)&theta,
                             (void*)&pbias, (void*)&fbias, (void*)&ft, (void*)&pt,
                             (void*)&tbf, (void*)&out };
            hipLaunchCooperativeKernel(reinterpret_cast<void*>(&k_fused<1>),
                                       dim3(n_blocks), dim3(256), args, 0, stream);
        } else {
            k_prep<<<648, 256, 0, stream>>>(feat, pos, theta, pbias, ft, pt, tbf);
            k_fused<0><<<n_blocks, 256, 0, stream>>>(feat, pos, nbr, theta, pbias, fbias,
                                                     ft, pt, tbf, out);
        }
    } else {
        k_fused<2><<<n_blocks, 256, 0, stream>>>(feat, pos, nbr, theta, pbias, fbias,
                                                 (unsigned short*)d_out, (float4*)d_out,
                                                 (unsigned short*)d_out, out);
    }
}